// Round 9
// baseline (170.323 us; speedup 1.0000x reference)
//
#include <hip/hip_runtime.h>

#define B_ 16
#define C_ 256
#define N_ 16384      // 128*128
#define R_ 16

typedef float f32x4 __attribute__((ext_vector_type(4)));

__device__ __forceinline__ float4 ldf4(const float* p) {
    return *reinterpret_cast<const float4*>(p);
}

// ---------------------------------------------------------------------------
// K1: partial colsum over a 128-channel half.  part[(b*2+half)][n].
// grid (B_, 16, 2) x 256 thr: block owns 1024 consecutive n, loops 128 c.
// Pure register accumulation, 1 KiB/wave-instr coalesced loads, no LDS.
// ---------------------------------------------------------------------------
__global__ void k1_colsum(const float* __restrict__ x,
                          float* __restrict__ part) {
    const int b = blockIdx.x;
    const int tile = blockIdx.y;
    const int half = blockIdx.z;
    const int n0 = tile * 1024 + threadIdx.x * 4;
    const float* xb = x + ((size_t)b * C_ + half * 128) * N_ + n0;

    float4 acc = make_float4(0.f, 0.f, 0.f, 0.f);
#pragma unroll 8
    for (int c = 0; c < 128; ++c) {
        float4 v = ldf4(xb + (size_t)c * N_);
        acc.x += v.x; acc.y += v.y; acc.z += v.z; acc.w += v.w;
    }
    *reinterpret_cast<float4*>(part + (size_t)(b * 2 + half) * N_ + n0) = acc;
}

// ---------------------------------------------------------------------------
// K2: v[b,c] = (P - (T/N)*RS) / ((N-1)*C) in ONE pass over the row:
//   cs[n] = part0[n]+part1[n];  P += x*cs;  RS += x;  T += cs.
// grid (C_, B_) x 256 thr (4096 blocks, 16/CU).  x row is L3-resident in
// steady state (kC's read re-allocates it; kC's out-writes are nt).
// T is recomputed per block in identical FP order -> deterministic.
// ---------------------------------------------------------------------------
__global__ void k2_v(const float* __restrict__ x,
                     const float* __restrict__ part,
                     float* __restrict__ v) {
    const int c = blockIdx.x;
    const int b = blockIdx.y;
    const int t = threadIdx.x;

    const float* xr = x + ((size_t)b * C_ + c) * N_;
    const float* p0 = part + (size_t)(b * 2 + 0) * N_;
    const float* p1 = part + (size_t)(b * 2 + 1) * N_;

    float P = 0.f, RS = 0.f, Tacc = 0.f;
#pragma unroll 4
    for (int n = t * 4; n < N_; n += 1024) {
        float4 xv = ldf4(xr + n);
        float4 a = ldf4(p0 + n);
        float4 bb = ldf4(p1 + n);
        float4 cs = make_float4(a.x + bb.x, a.y + bb.y, a.z + bb.z, a.w + bb.w);
        P += xv.x * cs.x + xv.y * cs.y + xv.z * cs.z + xv.w * cs.w;
        RS += xv.x + xv.y + xv.z + xv.w;
        Tacc += cs.x + cs.y + cs.z + cs.w;
    }

#pragma unroll
    for (int off = 32; off; off >>= 1) {
        P    += __shfl_down(P, off, 64);
        RS   += __shfl_down(RS, off, 64);
        Tacc += __shfl_down(Tacc, off, 64);
    }
    __shared__ float redP[4], redR[4], redT[4];
    if ((t & 63) == 0) {
        redP[t >> 6] = P; redR[t >> 6] = RS; redT[t >> 6] = Tacc;
    }
    __syncthreads();
    if (t == 0) {
        const float Pf = redP[0] + redP[1] + redP[2] + redP[3];
        const float RSf = redR[0] + redR[1] + redR[2] + redR[3];
        const float Tf = redT[0] + redT[1] + redT[2] + redT[3];
        const float denom = (float)(N_ - 1) * (float)C_;
        v[b * C_ + c] = (Pf - (Tf / (float)N_) * RSf) / denom;
    }
}

// ---------------------------------------------------------------------------
// kB: MLP only.  grid(B_) x 256, thread = c.
// ---------------------------------------------------------------------------
__global__ void kB(const float* __restrict__ v,
                   const float* __restrict__ w1, const float* __restrict__ b1,
                   const float* __restrict__ w2, const float* __restrict__ b2,
                   float* __restrict__ gate) {
    const int b = blockIdx.x;
    const int t = threadIdx.x;   // channel c

    __shared__ float vl[C_];
    vl[t] = v[b * C_ + t];
    __syncthreads();

    __shared__ float hpart[R_][16];
    __shared__ float h1[R_];
    {
        const int i = t >> 4, cc = t & 15;
        float a = 0.f;
#pragma unroll
        for (int k = 0; k < 16; ++k)
            a += vl[(cc << 4) + k] * w1[i * C_ + (cc << 4) + k];
        hpart[i][cc] = a;
    }
    __syncthreads();
    if (t < R_) {
        float a = b1[t];
#pragma unroll
        for (int k = 0; k < 16; ++k) a += hpart[t][k];
        h1[t] = a > 0.f ? a : 0.f;
    }
    __syncthreads();

    float a = b2[t];
#pragma unroll
    for (int i = 0; i < R_; ++i) a += h1[i] * w2[t * R_ + i];
    gate[b * C_ + t] = 1.f / (1.f + __expf(-a));
}

// ---------------------------------------------------------------------------
// kC: out = x * gate[b,c]; non-temporal stores keep x L3-resident.
// ---------------------------------------------------------------------------
__global__ void kC(const float* __restrict__ x,
                   const float* __restrict__ gate,
                   float* __restrict__ out) {
    const size_t total4 = (size_t)B_ * C_ * N_ / 4;
    for (size_t i = (size_t)blockIdx.x * blockDim.x + threadIdx.x; i < total4;
         i += (size_t)gridDim.x * blockDim.x) {
        const int bc = (int)(i >> 12);           // N_/4 = 4096 float4 per (b,c)
        const float g = gate[bc];
        float4 vx = reinterpret_cast<const float4*>(x)[i];
        f32x4 r;
        r.x = vx.x * g; r.y = vx.y * g; r.z = vx.z * g; r.w = vx.w * g;
        __builtin_nontemporal_store(r, reinterpret_cast<f32x4*>(out) + i);
    }
}

extern "C" void kernel_launch(void* const* d_in, const int* in_sizes, int n_in,
                              void* d_out, int out_size, void* d_ws, size_t ws_size,
                              hipStream_t stream) {
    (void)in_sizes; (void)n_in; (void)out_size; (void)ws_size;
    const float* x  = (const float*)d_in[0];
    const float* w1 = (const float*)d_in[1];
    const float* b1 = (const float*)d_in[2];
    const float* w2 = (const float*)d_in[3];
    const float* b2 = (const float*)d_in[4];
    float* out = (float*)d_out;

    float* ws   = (float*)d_ws;
    float* part = ws;                            // 2*B_*N_ = 524288 floats
    float* v    = part + (size_t)2 * B_ * N_;    // B_*C_
    float* gate = v + B_ * C_;                   // B_*C_

    hipLaunchKernelGGL(k1_colsum, dim3(B_, 16, 2), dim3(256), 0, stream,
                       x, part);
    hipLaunchKernelGGL(k2_v, dim3(C_, B_), dim3(256), 0, stream,
                       x, part, v);
    hipLaunchKernelGGL(kB, dim3(B_), dim3(256), 0, stream,
                       v, w1, b1, w2, b2, gate);
    hipLaunchKernelGGL(kC, dim3(2048), dim3(256), 0, stream,
                       x, gate, out);
}

// Round 10
// 155.420 us; speedup vs baseline: 1.0959x; 1.0959x over previous
//
#include <hip/hip_runtime.h>

#define B_ 16
#define C_ 256
#define N_ 16384      // 128*128
#define R_ 16
#define SUB_ 32       // n per subtile

typedef float f32x4 __attribute__((ext_vector_type(4)));

__device__ __forceinline__ float4 ldf4(const float* p) {
    return *reinterpret_cast<const float4*>(p);
}

// ---------------------------------------------------------------------------
// kA: fused stats pass, register-resident + pipelined.
// Thread (kq=t&7, crow=t>>3) owns n-slots {4kq..4kq+3} and channels
// {crow+32r} in pre[8].  colsum: VALU 8-channel partial -> shfl_xor butterfly
// over lane bits 3/4/5 (in-wave 8 crows) -> 1 f4 LDS write/wave -> 4 f4 reads
// (cross-wave sum) -> broadcast cl.  accP[r] += pre[r].cl; accRS[r] += sum.
// Subtile s+1's loads are issued BEFORE consuming s (ping-pong regs), and all
// barriers are raw s_barrier + lgkmcnt-only waits -> 8 loads always in
// flight, never a vmcnt(0) drain (R8-proven pattern).
// LDS 512 B; ~6 DS ops/thread/subtile (vs ~48 in the R4 LDS-tile version).
// ---------------------------------------------------------------------------
template<int NSUB>
__global__ __launch_bounds__(256)
void kA(const float* __restrict__ x,
        float* __restrict__ Ppart,
        float* __restrict__ RSpart,
        int blocksPerBatch) {
    const int blk = blockIdx.x;
    const int b = blockIdx.y;
    const int t = threadIdx.x;
    const int kq = t & 7;      // n-slot (float4) within subtile
    const int crow = t >> 3;   // 0..31 (wave w covers crows 8w..8w+7)
    const int lane = t & 63;
    const int wave = t >> 6;

    __shared__ float cw[4][8][4];   // [wave][kq][j] wave-partial colsums

    const float* xb = x + (size_t)b * C_ * N_
                    + (size_t)blk * (NSUB * SUB_) + (kq << 2);

    float4 pA[8], pB[8];
    float accP[8], accRS[8];
#pragma unroll
    for (int r = 0; r < 8; ++r) { accP[r] = 0.f; accRS[r] = 0.f; }

#pragma unroll
    for (int r = 0; r < 8; ++r)
        pA[r] = ldf4(xb + (size_t)(crow + (r << 5)) * N_);

#define PHASE(CUR, NXT, S)                                                     \
    {                                                                          \
        if ((S) + 1 < NSUB) {                                                  \
            _Pragma("unroll")                                                  \
            for (int r = 0; r < 8; ++r)                                        \
                NXT[r] = ldf4(xb + (size_t)(crow + (r << 5)) * N_              \
                              + ((S) + 1) * SUB_);                             \
        }                                                                      \
        /* per-thread 8-channel colsum partial (auto-wait = vmcnt(8)) */       \
        float4 cs = CUR[0];                                                    \
        _Pragma("unroll")                                                      \
        for (int r = 1; r < 8; ++r) {                                          \
            cs.x += CUR[r].x; cs.y += CUR[r].y;                                \
            cs.z += CUR[r].z; cs.w += CUR[r].w;                                \
        }                                                                      \
        _Pragma("unroll")                                                      \
        for (int m = 8; m <= 32; m <<= 1) {                                    \
            cs.x += __shfl_xor(cs.x, m, 64);                                   \
            cs.y += __shfl_xor(cs.y, m, 64);                                   \
            cs.z += __shfl_xor(cs.z, m, 64);                                   \
            cs.w += __shfl_xor(cs.w, m, 64);                                   \
        }                                                                      \
        if (lane < 8)                                                          \
            *reinterpret_cast<float4*>(&cw[wave][lane][0]) =                   \
                make_float4(cs.x, cs.y, cs.z, cs.w);                           \
        asm volatile("s_waitcnt lgkmcnt(0)" ::: "memory");                     \
        __builtin_amdgcn_s_barrier();                                          \
        float4 c0 = *reinterpret_cast<const float4*>(&cw[0][kq][0]);           \
        float4 c1 = *reinterpret_cast<const float4*>(&cw[1][kq][0]);           \
        float4 c2 = *reinterpret_cast<const float4*>(&cw[2][kq][0]);           \
        float4 c3 = *reinterpret_cast<const float4*>(&cw[3][kq][0]);           \
        float4 cl = make_float4(c0.x + c1.x + c2.x + c3.x,                     \
                                c0.y + c1.y + c2.y + c3.y,                     \
                                c0.z + c1.z + c2.z + c3.z,                     \
                                c0.w + c1.w + c2.w + c3.w);                    \
        _Pragma("unroll")                                                      \
        for (int r = 0; r < 8; ++r) {                                          \
            accP[r] += CUR[r].x * cl.x + CUR[r].y * cl.y                       \
                     + CUR[r].z * cl.z + CUR[r].w * cl.w;                      \
            accRS[r] += CUR[r].x + CUR[r].y + CUR[r].z + CUR[r].w;             \
        }                                                                      \
        asm volatile("s_waitcnt lgkmcnt(0)" ::: "memory");                     \
        __builtin_amdgcn_s_barrier(); /* cw reads done before next write */    \
    }

    for (int s = 0; s < NSUB; s += 2) {
        PHASE(pA, pB, s)
        PHASE(pB, pA, s + 1)
    }
#undef PHASE

    // fold the 8 kq-lanes (bits 0,1,2): full block-partial per channel
#pragma unroll
    for (int r = 0; r < 8; ++r) {
#pragma unroll
        for (int m = 1; m <= 4; m <<= 1) {
            accP[r]  += __shfl_xor(accP[r],  m, 64);
            accRS[r] += __shfl_xor(accRS[r], m, 64);
        }
    }
    if (kq == 0) {
        const size_t base = ((size_t)b * blocksPerBatch + blk) * C_;
#pragma unroll
        for (int r = 0; r < 8; ++r) {
            Ppart [base + crow + (r << 5)] = accP[r];
            RSpart[base + crow + (r << 5)] = accRS[r];
        }
    }
}

// ---------------------------------------------------------------------------
// kB: reduce partials -> v -> fused MLP -> gate.  grid(B_) x 256, thread = c.
// ---------------------------------------------------------------------------
__global__ void kB(const float* __restrict__ Ppart,
                   const float* __restrict__ RSpart,
                   const float* __restrict__ w1, const float* __restrict__ b1,
                   const float* __restrict__ w2, const float* __restrict__ b2,
                   float* __restrict__ gate, int blocksPerBatch) {
    const int b = blockIdx.x;
    const int t = threadIdx.x;   // channel c

    float P = 0.f, RS = 0.f;
    for (int k = 0; k < blocksPerBatch; ++k) {
        P  += Ppart [((size_t)b * blocksPerBatch + k) * C_ + t];
        RS += RSpart[((size_t)b * blocksPerBatch + k) * C_ + t];
    }

    __shared__ float red[4];
    float s = RS;
#pragma unroll
    for (int off = 32; off; off >>= 1) s += __shfl_down(s, off, 64);
    if ((t & 63) == 0) red[t >> 6] = s;
    __syncthreads();
    const float T = red[0] + red[1] + red[2] + red[3];
    const float M = T / (float)N_;
    const float denom = (float)(N_ - 1) * (float)C_;

    __shared__ float vl[C_];
    vl[t] = (P - M * RS) / denom;
    __syncthreads();

    __shared__ float hpart[R_][16];
    __shared__ float h1[R_];
    {
        const int i = t >> 4, cc = t & 15;
        float a = 0.f;
#pragma unroll
        for (int k = 0; k < 16; ++k)
            a += vl[(cc << 4) + k] * w1[i * C_ + (cc << 4) + k];
        hpart[i][cc] = a;
    }
    __syncthreads();
    if (t < R_) {
        float a = b1[t];
#pragma unroll
        for (int k = 0; k < 16; ++k) a += hpart[t][k];
        h1[t] = a > 0.f ? a : 0.f;
    }
    __syncthreads();

    float a = b2[t];
#pragma unroll
    for (int i = 0; i < R_; ++i) a += h1[i] * w2[t * R_ + i];
    gate[b * C_ + t] = 1.f / (1.f + __expf(-a));
}

// ---------------------------------------------------------------------------
// kC: out = x * gate[b,c]; non-temporal stores (proven).
// ---------------------------------------------------------------------------
__global__ void kC(const float* __restrict__ x,
                   const float* __restrict__ gate,
                   float* __restrict__ out) {
    const size_t total4 = (size_t)B_ * C_ * N_ / 4;
    for (size_t i = (size_t)blockIdx.x * blockDim.x + threadIdx.x; i < total4;
         i += (size_t)gridDim.x * blockDim.x) {
        const int bc = (int)(i >> 12);           // N_/4 = 4096 float4 per (b,c)
        const float g = gate[bc];
        float4 vx = reinterpret_cast<const float4*>(x)[i];
        f32x4 r;
        r.x = vx.x * g; r.y = vx.y * g; r.z = vx.z * g; r.w = vx.w * g;
        __builtin_nontemporal_store(r, reinterpret_cast<f32x4*>(out) + i);
    }
}

extern "C" void kernel_launch(void* const* d_in, const int* in_sizes, int n_in,
                              void* d_out, int out_size, void* d_ws, size_t ws_size,
                              hipStream_t stream) {
    (void)in_sizes; (void)n_in; (void)out_size; (void)ws_size;
    const float* x  = (const float*)d_in[0];
    const float* w1 = (const float*)d_in[1];
    const float* b1 = (const float*)d_in[2];
    const float* w2 = (const float*)d_in[3];
    const float* b2 = (const float*)d_in[4];
    float* out = (float*)d_out;

    const int bpb = 64;   // blocks per batch

    float* ws     = (float*)d_ws;
    float* Ppart  = ws;                                    // B_*bpb*C_
    float* RSpart = Ppart + (size_t)B_ * bpb * C_;         // B_*bpb*C_
    float* gate   = RSpart + (size_t)B_ * bpb * C_;        // B_*C_

    hipLaunchKernelGGL((kA<8>), dim3(bpb, B_), dim3(256), 0, stream,
                       x, Ppart, RSpart, bpb);
    hipLaunchKernelGGL(kB, dim3(B_), dim3(256), 0, stream,
                       Ppart, RSpart, w1, b1, w2, b2, gate, bpb);
    hipLaunchKernelGGL(kC, dim3(2048), dim3(256), 0, stream,
                       x, gate, out);
}